// Round 1
// baseline (70.272 us; speedup 1.0000x reference)
//
#include <hip/hip_runtime.h>

#define BATCH 512
#define FEATURES 256
#define NBITS 8
#define ENC 2048
#define HIDDEN 8192
#define CLASSES 1000
#define THRESH 16

typedef unsigned long long u64;
typedef unsigned int u32;

// -------- workspace layout (bytes) --------
// a0t   : ENC rows x 64 bytes (512-bit batch mask per encoded column) = 131072
// a1bm  : BATCH x 128 u64 (batch-major layer-1 active bitmap)          = 524288
// a2bm  : BATCH x 128 u64                                              = 524288
// cnt1  : BATCH u32                                                    = 2048
#define OFF_A0T   0
#define OFF_A1BM  131072
#define OFF_A2BM  (131072 + 524288)
#define OFF_CNT1  (131072 + 2*524288)

__global__ void zero_kernel(u32* p, int n) {
    int i = blockIdx.x * blockDim.x + threadIdx.x;
    if (i < n) p[i] = 0u;
}

// Encode x -> transposed bit columns. Thread (j, w) builds 32-batch word w of
// encoded column j. Bit layout: byte l of row j holds batches 8l..8l+7.
__global__ void encode_kernel(const float* __restrict__ x, u32* __restrict__ a0t) {
    int id = blockIdx.x * blockDim.x + threadIdx.x;
    if (id >= ENC * 16) return;
    int j = id >> 4;            // encoded column 0..2047
    int w = id & 15;            // 32-batch word 0..15
    int f = j >> 3;             // feature
    int bit = j & 7;            // gray bit index
    u32 m = 0;
    for (int i = 0; i < 32; ++i) {
        int b = w * 32 + i;
        float v = x[b * FEATURES + f];
        v = fminf(fmaxf(v, 0.0f), 1.0f);
        int lvl = (int)rintf(v * 255.0f);       // round-half-even == np.round
        int g = lvl ^ (lvl >> 1);
        m |= ((u32)((g >> bit) & 1)) << i;
    }
    a0t[j * 16 + w] = m;
}

// One wave per hidden-1 neuron: scan W1 row, for each nonzero (sign s, col j)
// update 512 per-batch int accumulators (8 per lane). Then threshold and emit
// batch-major active bits + per-batch counts.
__global__ __launch_bounds__(256) void z1_kernel(const float* __restrict__ W1,
                                                 const unsigned char* __restrict__ a0t,
                                                 u64* __restrict__ a1bm,
                                                 u32* __restrict__ cnt1) {
    int wid  = threadIdx.x >> 6;
    int lane = threadIdx.x & 63;
    int n = blockIdx.x * 4 + wid;
    const float* row = W1 + (size_t)n * ENC;

    int acc[8];
#pragma unroll
    for (int k = 0; k < 8; ++k) acc[k] = 0;

    for (int it = 0; it < ENC / 64; ++it) {
        float v = row[it * 64 + lane];
        u64 m = __ballot(v != 0.0f);
        while (m) {
            int src = __ffsll(m) - 1;
            m &= m - 1;
            float vs = __shfl(v, src);
            int s = (vs > 0.0f) ? 1 : -1;
            int j = it * 64 + src;
            unsigned byte = a0t[(size_t)j * 64 + lane];
#pragma unroll
            for (int k = 0; k < 8; ++k) acc[k] += ((byte >> k) & 1) ? s : 0;
        }
    }

    unsigned outb = 0;
#pragma unroll
    for (int k = 0; k < 8; ++k)
        if (acc[k] >= THRESH) outb |= (1u << k);

    while (outb) {
        int k = __ffs(outb) - 1;
        outb &= outb - 1;
        int b = lane * 8 + k;
        atomicAdd(&cnt1[b], 1u);
        atomicOr(&a1bm[(size_t)b * 128 + (n >> 6)], 1ull << (n & 63));
    }
}

// Layer 2: per batch. If cnt1[b] < 16, z2 row provably < 16 everywhere
// (W2 entries <= +1) -> a2 = 0 with zero W2 traffic. Else exact gather.
__global__ __launch_bounds__(256) void z2_kernel(const float* __restrict__ W2,
                                                 const u64* __restrict__ a1bm,
                                                 u64* __restrict__ a2bm,
                                                 const u32* __restrict__ cnt1) {
    int b = blockIdx.x;
    u64* outb = a2bm + (size_t)b * 128;
    if (cnt1[b] < THRESH) {
        for (int i = threadIdx.x; i < 128; i += 256) outb[i] = 0ull;
        return;
    }
    __shared__ int act[HIDDEN];
    __shared__ int nact;
    if (threadIdx.x == 0) {
        int cnt = 0;
        for (int wv = 0; wv < 128; ++wv) {
            u64 m = a1bm[(size_t)b * 128 + wv];
            while (m) { int r = __ffsll(m) - 1; m &= m - 1; act[cnt++] = wv * 64 + r; }
        }
        nact = cnt;
    }
    __syncthreads();
    int na = nact;
    int wid = threadIdx.x >> 6, lane = threadIdx.x & 63;
    for (int chunk = 0; chunk < HIDDEN; chunk += 256) {
        int n = chunk + threadIdx.x;
        int z = 0;
        for (int i = 0; i < na; ++i) z += (int)W2[(size_t)n * HIDDEN + act[i]];
        u64 bal = __ballot(z >= THRESH);
        if (lane == 0) outb[(chunk >> 6) + wid] = bal;
    }
}

// out[b,:] = sum_{n in act1[b]} Wout0[n,:] + sum_{n in act2[b]} Wout1[n,:]
// Deterministic ascending-n order.
__global__ __launch_bounds__(256) void out_kernel(const float* __restrict__ Wout,
                                                  const u64* __restrict__ a1bm,
                                                  const u64* __restrict__ a2bm,
                                                  float* __restrict__ outp) {
    int b = blockIdx.x;
    __shared__ int act[HIDDEN];
    __shared__ int nact;
    float s[4] = {0.f, 0.f, 0.f, 0.f};

    for (int layer = 0; layer < 2; ++layer) {
        const u64* bm = (layer == 0 ? a1bm : a2bm) + (size_t)b * 128;
        const float* W = Wout + (size_t)layer * HIDDEN * CLASSES;
        __syncthreads();   // protect act[] reuse across layers
        if (threadIdx.x == 0) {
            int cnt = 0;
            for (int wv = 0; wv < 128; ++wv) {
                u64 m = bm[wv];
                while (m) { int r = __ffsll(m) - 1; m &= m - 1; act[cnt++] = wv * 64 + r; }
            }
            nact = cnt;
        }
        __syncthreads();
        int na = nact;
        for (int i = 0; i < na; ++i) {
            const float* wr = W + (size_t)act[i] * CLASSES;
#pragma unroll
            for (int q = 0; q < 4; ++q) {
                int c = threadIdx.x + q * 256;
                if (c < CLASSES) s[q] += wr[c];
            }
        }
    }
#pragma unroll
    for (int q = 0; q < 4; ++q) {
        int c = threadIdx.x + q * 256;
        if (c < CLASSES) outp[(size_t)b * CLASSES + c] = s[q];
    }
}

// argmax with numpy first-index tie-breaking; one wave per batch row.
__global__ void argmax_kernel(const float* __restrict__ outp, float* __restrict__ pred) {
    int b = blockIdx.x;
    int lane = threadIdx.x;
    float best = -__builtin_inff();
    int bi = CLASSES;
    for (int c = lane; c < CLASSES; c += 64) {
        float v = outp[(size_t)b * CLASSES + c];
        if (v > best) { best = v; bi = c; }
    }
    for (int off = 32; off; off >>= 1) {
        float ov = __shfl_xor(best, off);
        int oi   = __shfl_xor(bi, off);
        if (ov > best || (ov == best && oi < bi)) { best = ov; bi = oi; }
    }
    if (lane == 0) pred[b] = (float)bi;
}

extern "C" void kernel_launch(void* const* d_in, const int* in_sizes, int n_in,
                              void* d_out, int out_size, void* d_ws, size_t ws_size,
                              hipStream_t stream) {
    (void)in_sizes; (void)n_in; (void)out_size; (void)ws_size;
    const float* x    = (const float*)d_in[0];
    const float* W1   = (const float*)d_in[1];
    const float* W2   = (const float*)d_in[2];
    const float* Wout = (const float*)d_in[3];

    float* pred = (float*)d_out;          // 512 predictions (as float)
    float* outp = (float*)d_out + BATCH;  // 512 x 1000 logits

    char* ws = (char*)d_ws;
    u32* a0t_w = (u32*)(ws + OFF_A0T);
    unsigned char* a0t = (unsigned char*)(ws + OFF_A0T);
    u64* a1bm = (u64*)(ws + OFF_A1BM);
    u64* a2bm = (u64*)(ws + OFF_A2BM);
    u32* cnt1 = (u32*)(ws + OFF_CNT1);

    // zero a1bm + a2bm + cnt1 (contiguous span)
    int nzero = (2 * 524288 + 2048) / 4;
    zero_kernel<<<(nzero + 255) / 256, 256, 0, stream>>>((u32*)(ws + OFF_A1BM), nzero);

    encode_kernel<<<(ENC * 16 + 255) / 256, 256, 0, stream>>>(x, a0t_w);
    z1_kernel<<<HIDDEN / 4, 256, 0, stream>>>(W1, a0t, a1bm, cnt1);
    z2_kernel<<<BATCH, 256, 0, stream>>>(W2, a1bm, a2bm, cnt1);
    out_kernel<<<BATCH, 256, 0, stream>>>(Wout, a1bm, a2bm, outp);
    argmax_kernel<<<BATCH, 64, 0, stream>>>(outp, pred);
}

// Round 2
// 50.179 us; speedup vs baseline: 1.4004x; 1.4004x over previous
//
#include <hip/hip_runtime.h>

#define BATCH 512
#define FEATURES 256
#define ENC 2048
#define HIDDEN 8192
#define CLASSES 1000
#define THRESH 16
#define PAIR_CAP 65536
#define MAXACT 256

typedef unsigned long long u64;
typedef unsigned int u32;

// -------- workspace layout (bytes) --------
// a0t    : ENC rows x 64 bytes (512-bit batch mask per encoded column) = 131072
// npairs : 1 u32
// pairs  : PAIR_CAP u32, entry = (b << 13) | n
#define OFF_A0T    0
#define OFF_NPAIRS 131072
#define OFF_PAIRS  131328

// Encode x -> transposed bit columns + zero the pair counter.
// Thread (w, f): computes gray code for feature f, batches w*32..w*32+31,
// emits 8 bit-plane words. Loads coalesced across f.
__global__ __launch_bounds__(256) void prep_kernel(const float* __restrict__ x,
                                                   u32* __restrict__ a0t,
                                                   u32* __restrict__ npairs) {
    int id = blockIdx.x * 256 + threadIdx.x;   // 0..4095
    if (id == 0) npairs[0] = 0;
    int w = id >> 8;                            // 32-batch word 0..15
    int f = id & 255;                           // feature
    u32 m0 = 0, m1 = 0, m2 = 0, m3 = 0, m4 = 0, m5 = 0, m6 = 0, m7 = 0;
    for (int i = 0; i < 32; ++i) {
        int b = w * 32 + i;
        float v = x[b * FEATURES + f];
        v = fminf(fmaxf(v, 0.0f), 1.0f);
        int lvl = (int)rintf(v * 255.0f);       // round-half-even == np.round
        int g = lvl ^ (lvl >> 1);
        u32 bit = 1u << i;
        if (g & 1)   m0 |= bit;
        if (g & 2)   m1 |= bit;
        if (g & 4)   m2 |= bit;
        if (g & 8)   m3 |= bit;
        if (g & 16)  m4 |= bit;
        if (g & 32)  m5 |= bit;
        if (g & 64)  m6 |= bit;
        if (g & 128) m7 |= bit;
    }
    int base = f * 8;        // encoded column = f*8 + bit
    a0t[(base + 0) * 16 + w] = m0;
    a0t[(base + 1) * 16 + w] = m1;
    a0t[(base + 2) * 16 + w] = m2;
    a0t[(base + 3) * 16 + w] = m3;
    a0t[(base + 4) * 16 + w] = m4;
    a0t[(base + 5) * 16 + w] = m5;
    a0t[(base + 6) * 16 + w] = m6;
    a0t[(base + 7) * 16 + w] = m7;
}

// One wave per hidden-1 neuron. float4 W1 loads (16 B/lane). Sign ballots
// (no shfl in pop loop). 8 per-batch int accumulators per lane. Active
// (b,n) pairs appended to a compact global list.
__global__ __launch_bounds__(256) void z1_kernel(const float* __restrict__ W1,
                                                 const unsigned char* __restrict__ a0t,
                                                 u32* __restrict__ pairs,
                                                 u32* __restrict__ npairs) {
    int wid  = threadIdx.x >> 6;
    int lane = threadIdx.x & 63;
    int n = blockIdx.x * 4 + wid;
    const float4* rowv = reinterpret_cast<const float4*>(W1 + (size_t)n * ENC);

    int acc[8];
#pragma unroll
    for (int k = 0; k < 8; ++k) acc[k] = 0;

    for (int it = 0; it < ENC / 256; ++it) {   // 8 iterations
        float4 v = rowv[it * 64 + lane];
#pragma unroll
        for (int c = 0; c < 4; ++c) {
            float vc = (c == 0) ? v.x : (c == 1) ? v.y : (c == 2) ? v.z : v.w;
            u64 mp = __ballot(vc > 0.0f);
            u64 mn = __ballot(vc < 0.0f);
            while (mp) {
                int src = __ffsll(mp) - 1; mp &= mp - 1;
                unsigned byte = a0t[(size_t)(it * 256 + src * 4 + c) * 64 + lane];
#pragma unroll
                for (int k = 0; k < 8; ++k) acc[k] += (byte >> k) & 1;
            }
            while (mn) {
                int src = __ffsll(mn) - 1; mn &= mn - 1;
                unsigned byte = a0t[(size_t)(it * 256 + src * 4 + c) * 64 + lane];
#pragma unroll
                for (int k = 0; k < 8; ++k) acc[k] -= (byte >> k) & 1;
            }
        }
    }

#pragma unroll
    for (int k = 0; k < 8; ++k) {
        if (acc[k] >= THRESH) {
            int b = lane * 8 + k;
            u32 pos = atomicAdd(npairs, 1u);
            if (pos < PAIR_CAP) pairs[pos] = ((u32)b << 13) | (u32)n;
        }
    }
}

// One block per batch: collect+sort active layer-1 neurons, inline layer-2
// (only touches W2 when >=16 layer-1 actives — W2 entries <= +1 make z2 < 16
// provable otherwise), accumulate Wout rows ascending (deterministic), write
// logits, fused argmax with numpy first-index tie-breaking.
__global__ __launch_bounds__(256) void out_kernel(const float* __restrict__ W2,
                                                  const float* __restrict__ Wout,
                                                  const u32* __restrict__ pairs,
                                                  const u32* __restrict__ npairs,
                                                  float* __restrict__ outp,
                                                  float* __restrict__ pred) {
    int b = blockIdx.x;
    int tid = threadIdx.x;
    __shared__ int act1[MAXACT];
    __shared__ int act2[MAXACT];
    __shared__ int n1s, n2s;
    __shared__ float rv[256];
    __shared__ int ri[256];

    if (tid == 0) {
        int tot = (int)npairs[0];
        if (tot > PAIR_CAP) tot = PAIR_CAP;
        int cnt = 0;
        for (int i = 0; i < tot; ++i) {
            u32 p = pairs[i];
            if ((int)(p >> 13) == b && cnt < MAXACT) act1[cnt++] = (int)(p & 8191u);
        }
        // insertion sort ascending (tiny counts)
        for (int i = 1; i < cnt; ++i) {
            int v = act1[i], k = i;
            while (k > 0 && act1[k - 1] > v) { act1[k] = act1[k - 1]; --k; }
            act1[k] = v;
        }
        n1s = cnt;
        n2s = 0;
    }
    __syncthreads();
    int na1 = n1s;

    if (na1 >= THRESH) {   // block-uniform rare path
        for (int nn = tid; nn < HIDDEN; nn += 256) {
            int z = 0;
            for (int i = 0; i < na1; ++i) z += (int)W2[(size_t)nn * HIDDEN + act1[i]];
            if (z >= THRESH) {
                int pos = atomicAdd(&n2s, 1);
                if (pos < MAXACT) act2[pos] = nn;
            }
        }
        __syncthreads();
        if (tid == 0) {
            int cnt = n2s; if (cnt > MAXACT) { cnt = MAXACT; n2s = cnt; }
            for (int i = 1; i < cnt; ++i) {
                int v = act2[i], k = i;
                while (k > 0 && act2[k - 1] > v) { act2[k] = act2[k - 1]; --k; }
                act2[k] = v;
            }
        }
        __syncthreads();
    }
    int na2 = n2s;

    float s0 = 0.f, s1 = 0.f, s2 = 0.f, s3 = 0.f;
    for (int i = 0; i < na1; ++i) {
        const float* wr = Wout + (size_t)act1[i] * CLASSES;   // layer 0
        s0 += wr[tid];
        s1 += wr[tid + 256];
        s2 += wr[tid + 512];
        if (tid + 768 < CLASSES) s3 += wr[tid + 768];
    }
    for (int i = 0; i < na2; ++i) {
        const float* wr = Wout + (size_t)HIDDEN * CLASSES + (size_t)act2[i] * CLASSES;
        s0 += wr[tid];
        s1 += wr[tid + 256];
        s2 += wr[tid + 512];
        if (tid + 768 < CLASSES) s3 += wr[tid + 768];
    }

    float* orow = outp + (size_t)b * CLASSES;
    orow[tid]       = s0;
    orow[tid + 256] = s1;
    orow[tid + 512] = s2;
    if (tid + 768 < CLASSES) orow[tid + 768] = s3;

    // fused argmax (numpy first-index tie-break: max v, min index)
    float best = s0; int bi = tid;
    if (s1 > best) { best = s1; bi = tid + 256; }
    if (s2 > best) { best = s2; bi = tid + 512; }
    if (tid + 768 < CLASSES && s3 > best) { best = s3; bi = tid + 768; }
    rv[tid] = best; ri[tid] = bi;
    __syncthreads();
    for (int off = 128; off; off >>= 1) {
        if (tid < off) {
            float ov = rv[tid + off]; int oi = ri[tid + off];
            if (ov > rv[tid] || (ov == rv[tid] && oi < ri[tid])) { rv[tid] = ov; ri[tid] = oi; }
        }
        __syncthreads();
    }
    if (tid == 0) pred[b] = (float)ri[0];
}

extern "C" void kernel_launch(void* const* d_in, const int* in_sizes, int n_in,
                              void* d_out, int out_size, void* d_ws, size_t ws_size,
                              hipStream_t stream) {
    (void)in_sizes; (void)n_in; (void)out_size; (void)ws_size;
    const float* x    = (const float*)d_in[0];
    const float* W1   = (const float*)d_in[1];
    const float* W2   = (const float*)d_in[2];
    const float* Wout = (const float*)d_in[3];

    float* pred = (float*)d_out;          // 512 predictions (as float)
    float* outp = (float*)d_out + BATCH;  // 512 x 1000 logits

    char* ws = (char*)d_ws;
    u32* a0t_w = (u32*)(ws + OFF_A0T);
    unsigned char* a0t = (unsigned char*)(ws + OFF_A0T);
    u32* npairs = (u32*)(ws + OFF_NPAIRS);
    u32* pairs  = (u32*)(ws + OFF_PAIRS);

    prep_kernel<<<16, 256, 0, stream>>>(x, a0t_w, npairs);
    z1_kernel<<<HIDDEN / 4, 256, 0, stream>>>(W1, a0t, pairs, npairs);
    out_kernel<<<BATCH, 256, 0, stream>>>(W2, Wout, pairs, npairs, outp, pred);
}

// Round 3
// 39.982 us; speedup vs baseline: 1.7576x; 1.2550x over previous
//
#include <hip/hip_runtime.h>

#define BATCH 512
#define FEATURES 256
#define ENC 2048
#define HIDDEN 8192
#define CLASSES 1000
#define THRESH 16
#define PAIR_CAP 65536
#define MAXACT 256

typedef unsigned long long u64;
typedef unsigned int u32;

// -------- workspace layout (bytes) --------
// a0t    : ENC rows x 64 bytes (512-bit batch mask per encoded column) = 131072
// npairs : 1 u32
// pairs  : PAIR_CAP u32, entry = (b << 13) | n
#define OFF_A0T    0
#define OFF_NPAIRS 131072
#define OFF_PAIRS  131328

// Encode x -> transposed bit columns + zero the pair counter.
__global__ __launch_bounds__(256) void prep_kernel(const float* __restrict__ x,
                                                   u32* __restrict__ a0t,
                                                   u32* __restrict__ npairs) {
    int id = blockIdx.x * 256 + threadIdx.x;   // 0..4095
    if (id == 0) npairs[0] = 0;
    int w = id >> 8;                            // 32-batch word 0..15
    int f = id & 255;                           // feature
    u32 m0 = 0, m1 = 0, m2 = 0, m3 = 0, m4 = 0, m5 = 0, m6 = 0, m7 = 0;
    for (int i = 0; i < 32; ++i) {
        int b = w * 32 + i;
        float v = x[b * FEATURES + f];
        v = fminf(fmaxf(v, 0.0f), 1.0f);
        int lvl = (int)rintf(v * 255.0f);       // round-half-even == np.round
        int g = lvl ^ (lvl >> 1);
        u32 bit = 1u << i;
        if (g & 1)   m0 |= bit;
        if (g & 2)   m1 |= bit;
        if (g & 4)   m2 |= bit;
        if (g & 8)   m3 |= bit;
        if (g & 16)  m4 |= bit;
        if (g & 32)  m5 |= bit;
        if (g & 64)  m6 |= bit;
        if (g & 128) m7 |= bit;
    }
    int base = f * 8;        // encoded column = f*8 + bit
    a0t[(base + 0) * 16 + w] = m0;
    a0t[(base + 1) * 16 + w] = m1;
    a0t[(base + 2) * 16 + w] = m2;
    a0t[(base + 3) * 16 + w] = m3;
    a0t[(base + 4) * 16 + w] = m4;
    a0t[(base + 5) * 16 + w] = m5;
    a0t[(base + 6) * 16 + w] = m6;
    a0t[(base + 7) * 16 + w] = m7;
}

// One wave per hidden-1 neuron, two-phase:
//  A) float4 scan of the W1 row; ballot+prefix compacts <=32 (col,sign)
//     entries into LDS.
//  B) unrolled loop over entries: scalar (readfirstlane) entry -> uniform
//     sign branch + SGPR-base byte load of the 64B batch-mask line; bit-sliced
//     carry-save counters (6 planes) for P (positives) and N (negatives).
//  Epilogue: z>=16 needs P>=16 <=> (p4|p5)!=0 — extract counts only there.
__global__ __launch_bounds__(256) void z1_kernel(const float* __restrict__ W1,
                                                 const unsigned char* __restrict__ a0t,
                                                 u32* __restrict__ pairs,
                                                 u32* __restrict__ npairs) {
    int wid  = threadIdx.x >> 6;
    int lane = threadIdx.x & 63;
    int n = blockIdx.x * 4 + wid;
    const float4* rowv = reinterpret_cast<const float4*>(W1 + (size_t)n * ENC);

    __shared__ int colsAll[4][40];
    int* cols = colsAll[wid];

    int cnt = 0;
    u64 lmask = (lane == 63) ? 0x7fffffffffffffffULL : ((1ULL << lane) - 1);
    for (int it = 0; it < 8; ++it) {
        float4 v = rowv[it * 64 + lane];
#pragma unroll
        for (int c = 0; c < 4; ++c) {
            float vc = (c == 0) ? v.x : (c == 1) ? v.y : (c == 2) ? v.z : v.w;
            u64 m = __ballot(vc != 0.0f);
            if (vc != 0.0f) {
                int pos = cnt + __popcll(m & lmask);
                cols[pos] = ((it * 256 + lane * 4 + c) << 1) | (vc < 0.0f ? 1 : 0);
            }
            cnt += __popcll(m);
        }
    }

    u32 p0 = 0, p1 = 0, p2 = 0, p3 = 0, p4 = 0, p5 = 0;
    u32 q0 = 0, q1 = 0, q2 = 0, q3 = 0, q4 = 0, q5 = 0;
#pragma unroll 4
    for (int i = 0; i < cnt; ++i) {
        int e = __builtin_amdgcn_readfirstlane(cols[i]);
        u32 m = a0t[(size_t)(e >> 1) * 64 + lane];
        if (e & 1) {   // negative sign (wave-uniform branch)
            u32 t;
            t = q0 & m; q0 ^= m; m = t;
            t = q1 & m; q1 ^= m; m = t;
            t = q2 & m; q2 ^= m; m = t;
            t = q3 & m; q3 ^= m; m = t;
            t = q4 & m; q4 ^= m; m = t;
            q5 ^= m;
        } else {
            u32 t;
            t = p0 & m; p0 ^= m; m = t;
            t = p1 & m; p1 ^= m; m = t;
            t = p2 & m; p2 ^= m; m = t;
            t = p3 & m; p3 ^= m; m = t;
            t = p4 & m; p4 ^= m; m = t;
            p5 ^= m;
        }
    }

    u32 cand = p4 | p5;     // bytes where P >= 16 possible
    while (cand) {
        int k = __ffs(cand) - 1;
        cand &= cand - 1;
        int P = ((p0 >> k) & 1) | (((p1 >> k) & 1) << 1) | (((p2 >> k) & 1) << 2) |
                (((p3 >> k) & 1) << 3) | (((p4 >> k) & 1) << 4) | (((p5 >> k) & 1) << 5);
        int N = ((q0 >> k) & 1) | (((q1 >> k) & 1) << 1) | (((q2 >> k) & 1) << 2) |
                (((q3 >> k) & 1) << 3) | (((q4 >> k) & 1) << 4) | (((q5 >> k) & 1) << 5);
        if (P - N >= THRESH) {
            int b = lane * 8 + k;
            u32 pos = atomicAdd(npairs, 1u);
            if (pos < PAIR_CAP) pairs[pos] = ((u32)b << 13) | (u32)n;
        }
    }
}

// One block per batch: PARALLEL pair collection, sort, inline provably-dead
// layer 2 (exact W2 gather only if >=16 layer-1 actives), Wout accumulation,
// logits write, fused argmax (numpy first-index tie-break).
__global__ __launch_bounds__(256) void out_kernel(const float* __restrict__ W2,
                                                  const float* __restrict__ Wout,
                                                  const u32* __restrict__ pairs,
                                                  const u32* __restrict__ npairs,
                                                  float* __restrict__ outp,
                                                  float* __restrict__ pred) {
    int b = blockIdx.x;
    int tid = threadIdx.x;
    __shared__ int act1[MAXACT];
    __shared__ int act2[MAXACT];
    __shared__ int n1s, n2s;
    __shared__ float rv[256];
    __shared__ int ri[256];

    if (tid == 0) { n1s = 0; n2s = 0; }
    __syncthreads();

    int tot = (int)npairs[0];
    if (tot > PAIR_CAP) tot = PAIR_CAP;
    for (int i = tid; i < tot; i += 256) {
        u32 p = pairs[i];
        if ((int)(p >> 13) == b) {
            int pos = atomicAdd(&n1s, 1);
            if (pos < MAXACT) act1[pos] = (int)(p & 8191u);
        }
    }
    __syncthreads();
    if (tid == 0) {
        int cnt = n1s;
        if (cnt > MAXACT) { cnt = MAXACT; n1s = cnt; }
        for (int i = 1; i < cnt; ++i) {             // deterministic ascending order
            int v = act1[i], k = i;
            while (k > 0 && act1[k - 1] > v) { act1[k] = act1[k - 1]; --k; }
            act1[k] = v;
        }
    }
    __syncthreads();
    int na1 = n1s;

    if (na1 >= THRESH) {   // block-uniform rare path (exactness guarantee)
        for (int nn = tid; nn < HIDDEN; nn += 256) {
            int z = 0;
            for (int i = 0; i < na1; ++i) z += (int)W2[(size_t)nn * HIDDEN + act1[i]];
            if (z >= THRESH) {
                int pos = atomicAdd(&n2s, 1);
                if (pos < MAXACT) act2[pos] = nn;
            }
        }
        __syncthreads();
        if (tid == 0) {
            int cnt = n2s; if (cnt > MAXACT) { cnt = MAXACT; n2s = cnt; }
            for (int i = 1; i < cnt; ++i) {
                int v = act2[i], k = i;
                while (k > 0 && act2[k - 1] > v) { act2[k] = act2[k - 1]; --k; }
                act2[k] = v;
            }
        }
        __syncthreads();
    }
    int na2 = n2s;

    float s0 = 0.f, s1 = 0.f, s2 = 0.f, s3 = 0.f;
    for (int i = 0; i < na1; ++i) {
        const float* wr = Wout + (size_t)act1[i] * CLASSES;   // layer 0
        s0 += wr[tid];
        s1 += wr[tid + 256];
        s2 += wr[tid + 512];
        if (tid + 768 < CLASSES) s3 += wr[tid + 768];
    }
    for (int i = 0; i < na2; ++i) {
        const float* wr = Wout + (size_t)HIDDEN * CLASSES + (size_t)act2[i] * CLASSES;
        s0 += wr[tid];
        s1 += wr[tid + 256];
        s2 += wr[tid + 512];
        if (tid + 768 < CLASSES) s3 += wr[tid + 768];
    }

    float* orow = outp + (size_t)b * CLASSES;
    orow[tid]       = s0;
    orow[tid + 256] = s1;
    orow[tid + 512] = s2;
    if (tid + 768 < CLASSES) orow[tid + 768] = s3;

    // fused argmax (max value, min index on ties == numpy)
    float best = s0; int bi = tid;
    if (s1 > best) { best = s1; bi = tid + 256; }
    if (s2 > best) { best = s2; bi = tid + 512; }
    if (tid + 768 < CLASSES && s3 > best) { best = s3; bi = tid + 768; }
    rv[tid] = best; ri[tid] = bi;
    __syncthreads();
    for (int off = 128; off; off >>= 1) {
        if (tid < off) {
            float ov = rv[tid + off]; int oi = ri[tid + off];
            if (ov > rv[tid] || (ov == rv[tid] && oi < ri[tid])) { rv[tid] = ov; ri[tid] = oi; }
        }
        __syncthreads();
    }
    if (tid == 0) pred[b] = (float)ri[0];
}

extern "C" void kernel_launch(void* const* d_in, const int* in_sizes, int n_in,
                              void* d_out, int out_size, void* d_ws, size_t ws_size,
                              hipStream_t stream) {
    (void)in_sizes; (void)n_in; (void)out_size; (void)ws_size;
    const float* x    = (const float*)d_in[0];
    const float* W1   = (const float*)d_in[1];
    const float* W2   = (const float*)d_in[2];
    const float* Wout = (const float*)d_in[3];

    float* pred = (float*)d_out;          // 512 predictions (as float)
    float* outp = (float*)d_out + BATCH;  // 512 x 1000 logits

    char* ws = (char*)d_ws;
    u32* a0t_w = (u32*)(ws + OFF_A0T);
    unsigned char* a0t = (unsigned char*)(ws + OFF_A0T);
    u32* npairs = (u32*)(ws + OFF_NPAIRS);
    u32* pairs  = (u32*)(ws + OFF_PAIRS);

    prep_kernel<<<16, 256, 0, stream>>>(x, a0t_w, npairs);
    z1_kernel<<<HIDDEN / 4, 256, 0, stream>>>(W1, a0t, pairs, npairs);
    out_kernel<<<BATCH, 256, 0, stream>>>(W2, Wout, pairs, npairs, outp, pred);
}